// Round 7
// baseline (124.366 us; speedup 1.0000x reference)
//
#include <hip/hip_runtime.h>
#include <math.h>

#define B_ 4
#define L_ 4096
#define D_ 256
#define A_ 64
#define M_ (B_*L_)   // 16384 flat rows

typedef _Float16 half4 __attribute__((ext_vector_type(4)));
typedef _Float16 half8 __attribute__((ext_vector_type(8)));
typedef __attribute__((ext_vector_type(4))) float floatx4;

__device__ __forceinline__ unsigned short f2h_(float f) {
    _Float16 h = (_Float16)f;
    return __builtin_bit_cast(unsigned short, h);
}

// async global->LDS, 16B per lane (emits global_load_lds_dwordx4)
__device__ __forceinline__ void gll16(const unsigned short* g, unsigned short* l) {
    __builtin_amdgcn_global_load_lds(
        (const __attribute__((address_space(1))) unsigned int*)g,
        (__attribute__((address_space(3))) unsigned int*)l, 16, 0, 0);
}

// ---------------------------------------------------------------------------
// wconv: W f32 [256][64] -> W^T fp16 [64][256]. Wq scaled by 1/ln2 (exp2
// softmax domain). grid (3), block 256.
// ---------------------------------------------------------------------------
__global__ __launch_bounds__(256) void wconv_kernel(
    const float* __restrict__ Wq, const float* __restrict__ Wk,
    const float* __restrict__ Wv, unsigned short* __restrict__ wt)
{
    const int w = blockIdx.x, t = threadIdx.x;
    const float* W = (w == 0) ? Wq : (w == 1) ? Wk : Wv;
    unsigned short* o = wt + w * A_ * D_;
    const float scale = (w == 0) ? 1.44269504f : 1.0f;
    __shared__ float T[A_ * 260];
    #pragma unroll
    for (int p = 0; p < 16; ++p) {
        int idx = p * 256 + t;
        int d = idx >> 4, a4 = (idx & 15) * 4;
        float4 v = *(const float4*)(W + d * A_ + a4);
        T[(a4 + 0) * 260 + d] = v.x * scale;
        T[(a4 + 1) * 260 + d] = v.y * scale;
        T[(a4 + 2) * 260 + d] = v.z * scale;
        T[(a4 + 3) * 260 + d] = v.w * scale;
    }
    __syncthreads();
    const int a = t >> 2, d0 = (t & 3) * 64;
    #pragma unroll
    for (int i = 0; i < 16; ++i) {
        float4 v = *(const float4*)(&T[a * 260 + d0 + 4 * i]);
        ushort4 s;
        s.x = f2h_(v.x); s.y = f2h_(v.y); s.z = f2h_(v.z); s.w = f2h_(v.w);
        *(ushort4*)(o + a * D_ + d0 + 4 * i) = s;
    }
}

// ---------------------------------------------------------------------------
// proj: one block per 32 x-rows computes ALL 3 projections (x staged once).
// grid (M/32), block 384 = 6 waves: wave = (w = wid>>1, mt = wid&1).
// q/k fp16 [M][64]; v fp16 TRANSPOSED [B][64][L].
// ---------------------------------------------------------------------------
__global__ __launch_bounds__(384) void proj_kernel(
    const float* __restrict__ x,           // [M][256] f32
    const unsigned short* __restrict__ wt, // [3][64][256] fp16 (W^T)
    unsigned short* __restrict__ qo,
    unsigned short* __restrict__ ko,
    unsigned short* __restrict__ vto)
{
    __shared__ __align__(16) unsigned short Xh[32 * 264];   // 16.5 KB
    __shared__ __align__(16) unsigned short Cst[6 * 1536];  // 18 KB
    const int t = threadIdx.x, m0 = blockIdx.x * 32;

    #pragma unroll
    for (int p = 0; p < 6; ++p) {
        int idx = p * 384 + t;
        if (idx < 2048) {
            int row = idx >> 6, col = (idx & 63) * 4;
            float4 v = *(const float4*)(x + (size_t)(m0 + row) * D_ + col);
            ushort4 s;
            s.x = f2h_(v.x); s.y = f2h_(v.y); s.z = f2h_(v.z); s.w = f2h_(v.w);
            *(ushort4*)(Xh + row * 264 + col) = s;
        }
    }
    __syncthreads();

    const int wid = t >> 6, lane = t & 63, c = lane & 15, g = lane >> 4;
    const int w = wid >> 1, mt = wid & 1;

    half8 xa[8];
    #pragma unroll
    for (int s = 0; s < 8; ++s)
        xa[s] = *(const half8*)(Xh + (16 * mt + c) * 264 + 32 * s + 8 * g);

    const unsigned short* wsrc = wt + w * A_ * D_;
    unsigned short* Cw = Cst + wid * 1536;
    #pragma unroll
    for (int nt = 0; nt < 4; ++nt) {
        floatx4 acc = {0.f, 0.f, 0.f, 0.f};
        #pragma unroll
        for (int s = 0; s < 8; ++s) {
            half8 wb = *(const half8*)(wsrc + (16 * nt + c) * D_ + 32 * s + 8 * g);
            acc = __builtin_amdgcn_mfma_f32_16x16x32_f16(xa[s], wb, acc, 0, 0, 0);
        }
        if (w < 2) {
            #pragma unroll
            for (int r = 0; r < 4; ++r)
                Cw[(4 * g + r) * 72 + 16 * nt + c] = f2h_(acc[r]);      // [m16][72]
        } else {
            #pragma unroll
            for (int r = 0; r < 4; ++r)
                Cw[(16 * nt + c) * 24 + 4 * g + r] = f2h_(acc[r]);      // [a64][24]
        }
    }

    if (w < 2) {
        unsigned short* o = (w == 0) ? qo : ko;
        const int row16 = lane >> 2, seg = lane & 3;
        uint4 d0 = *(const uint4*)(Cw + row16 * 72 + seg * 16);
        uint4 d1 = *(const uint4*)(Cw + row16 * 72 + seg * 16 + 8);
        unsigned short* p = o + (size_t)(m0 + 16 * mt + row16) * A_ + seg * 16;
        *(uint4*)(p) = d0;
        *(uint4*)(p + 8) = d1;
    }
    __syncthreads();
    if (t < 256) {
        const int a = t >> 2, quarter = t & 3;
        const int o = quarter * 8, mtv = o >> 4, idx = o & 15;
        uint4 d = *(const uint4*)(Cst + (4 + mtv) * 1536 + a * 24 + idx);
        const int bb = m0 >> 12, l0 = m0 & (L_ - 1);
        *(uint4*)(vto + ((size_t)(bb * A_ + a)) * L_ + l0 + o) = d;
    }
}

// ---------------------------------------------------------------------------
// attn: split-K flash, 128-q blocks, uniform chunks, DOUBLE-BUFFERED
// global_load_lds staging. grid (576) 1D, block 512 = 8 waves = 4 qsub x
// 2 ph (ph splits the 2 tiles of each iteration).
//
// Staging (m97/T3-minimum): per iteration, ONE __syncthreads; right after
// it, issue next-pair global_load_lds into buffer cur^1 (async, zero VGPR,
// vmcnt outstanding), then compute pair from buffer cur. The barrier's
// vmcnt(0) drain lands a full compute-phase after issue -> latency hidden.
// (Round-4 reg-prefetch spilled: VGPR 52->40 + 132 MB scratch writes.
// global_load_lds avoids registers entirely.)
//
// LDS: linear [64 rows][64 shorts] tiles (gll writes base+lane*16, rule
// #21: no padding allowed) x 2 tiles x 2 buffers x {K,V} = 64 KB.
// Bank fix: XOR swizzle byte ^= ((row&7)<<4) applied BOTH sides:
//   source: lane (row=t>>3, c8=t&7) loads global chunk c8^(row&7);
//   reads:  kf/va shorts offset low bits ^ (c&7)*8  (row&7 == c&7 since
//           row = 16*nt_or_at + c).
// Replaces the padded-72 layout (3.59M conflict cycles).
//
// Decomposition (round 5): per batch 32 q-tiles, T = 2qt+2 key tiles,
// nch = ceil(T/8) chunks, 144/batch, big chunks first; x=bx&7 -> XCD,
// b=x>>1. Emits UNNORMALIZED (O,m,l) per chunk j: poB[j][M][64], mlB[j][M].
// ---------------------------------------------------------------------------
__global__ __launch_bounds__(512, 4) void attn_kernel(
    const unsigned short* __restrict__ qb,  // [B][L][64] fp16 (x 1/ln2)
    const unsigned short* __restrict__ kb,  // [B][L][64] fp16
    const unsigned short* __restrict__ vt,  // [B][64][L] fp16
    float* __restrict__ poB,                // [8][M][64] partial O
    float2* __restrict__ mlB)               // [8][M] (m,l)
{
    __shared__ __align__(16) unsigned short smem[32768];  // 64 KB
    unsigned short* Ks = smem;              // 4 slots x 4096 shorts
    unsigned short* Vs = smem + 16384;      // 4 slots x 4096 shorts

    const int t    = threadIdx.x;
    const int lane = t & 63;
    const int wid  = t >> 6;          // 0..7
    const int qsub = wid >> 1;        // 0..3 -> 32-row group
    const int ph   = wid & 1;
    const int c    = lane & 15;
    const int g    = lane >> 4;
    const int csw  = (c & 7) * 8;     // read-side swizzle (shorts)

    // staging coords: 512 threads x 16B = one 8 KB tile
    const int srow = t >> 3, sc8 = t & 7;
    const int ssw  = (sc8 ^ (srow & 7)) * 8;   // pre-swizzled source chunk

    // ---- block id -> (b, qt, chunk j of nch) ----
    const int bx = blockIdx.x;
    const int x  = bx & 7, u = bx >> 3;
    const int b  = x >> 1;
    const int gch = 143 - (2 * u + (x & 1));    // reversed: big chunks first
    int m = 0;
    while (2 * (m + 1) * (m + 2) <= gch) ++m;   // uniform scalar, <=7 iters
    const int rem = gch - 2 * m * (m + 1);
    const int nch = m + 1;
    const int qt  = 4 * m + rem / nch;
    const int j   = rem % nch;
    const int T   = 2 * qt + 2;
    const int t0  = (j * T) / nch;
    const int t1  = ((j + 1) * T) / nch;
    const int nIt = (t1 - t0 + 1) >> 1;
    const int Tm2 = T - 2;

    const int q0    = qt * 128;
    const int qrow0 = q0 + 32 * qsub;
    const int qme0  = qrow0 + c;

    const size_t base  = (size_t)b * L_ * A_;
    const size_t vbase = (size_t)b * A_ * L_;

    half8 qf[2][2];
    #pragma unroll
    for (int f = 0; f < 2; ++f) {
        const unsigned short* qp = qb + base + (size_t)(qrow0 + 16 * f + c) * A_ + g * 8;
        qf[f][0] = *(const half8*)(qp);
        qf[f][1] = *(const half8*)(qp + 32);
    }

    floatx4 O4[2][4];
    #pragma unroll
    for (int f = 0; f < 2; ++f)
        #pragma unroll
        for (int at = 0; at < 4; ++at) O4[f][at] = (floatx4){0.f, 0.f, 0.f, 0.f};
    float m_[2] = {-INFINITY, -INFINITY};
    float l_[2] = {0.f, 0.f};

    // ---- async stage: tile kts -> slot (zero-register, pre-swizzled src) ----
    #define STAGE_KV(kts_, slot_) do {                                          \
        const int k0s_ = (kts_) << 6;                                           \
        gll16(kb + base + (size_t)(k0s_ + srow) * 64 + ssw,                     \
              Ks + (slot_) * 4096 + t * 8);                                     \
        gll16(vt + vbase + (size_t)srow * L_ + k0s_ + ssw,                      \
              Vs + (slot_) * 4096 + t * 8);                                     \
    } while (0)

    // prologue: fill buffer 0
    STAGE_KV(t0, 0);
    if (t0 + 1 < t1) STAGE_KV(t0 + 1, 1);

    int cur = 0;
    for (int it = 0; it < nIt; ++it) {
        __syncthreads();   // vmcnt(0)+lgkm drain: buf[cur] ready, buf[cur^1] free
        const int itb = t0 + 2 * it;
        if (it + 1 < nIt) {            // issue next pair NOW; hides under compute
            const int nb = itb + 2;
            STAGE_KV(nb, (cur ^ 1) * 2);
            if (nb + 1 < t1) STAGE_KV(nb + 1, (cur ^ 1) * 2 + 1);
        }

        const int kt = itb + ph;
        if (kt < t1) {
            const int k0 = kt << 6;
            const unsigned short* Kw = Ks + (cur * 2 + ph) * 4096;
            const unsigned short* Vw = Vs + (cur * 2 + ph) * 4096;

            half4 pf[2][4];
            #pragma unroll
            for (int f = 0; f < 2; ++f) {
                // ---- S^T = K . Q^T (frag f) ----
                floatx4 S4[4];
                #pragma unroll
                for (int nt = 0; nt < 4; ++nt) S4[nt] = (floatx4){0.f, 0.f, 0.f, 0.f};
                __builtin_amdgcn_s_setprio(1);
                #pragma unroll
                for (int s = 0; s < 2; ++s)
                    #pragma unroll
                    for (int nt = 0; nt < 4; ++nt) {
                        half8 kf = *(const half8*)(Kw + nt * 1024 + c * 64 +
                                                   ((s * 32 + g * 8) ^ csw));
                        S4[nt] = __builtin_amdgcn_mfma_f32_16x16x32_f16(kf, qf[f][s], S4[nt], 0, 0, 0);
                    }
                __builtin_amdgcn_s_setprio(0);

                // ---- causal mask: tiles >= T-2 straddle the 128-q diagonal ----
                if (kt >= Tm2) {
                    const int qme = qme0 + 16 * f;
                    #pragma unroll
                    for (int nt = 0; nt < 4; ++nt)
                        #pragma unroll
                        for (int r = 0; r < 4; ++r)
                            if (k0 + 16 * nt + 4 * g + r > qme) S4[nt][r] = -INFINITY;
                }

                // ---- online softmax (exp2 domain; per-lane q row) ----
                float tm = fmaxf(fmaxf(fmaxf(S4[0][0], S4[0][1]), fmaxf(S4[0][2], S4[0][3])),
                                 fmaxf(fmaxf(S4[1][0], S4[1][1]), fmaxf(S4[1][2], S4[1][3])));
                tm = fmaxf(tm, fmaxf(fmaxf(fmaxf(S4[2][0], S4[2][1]), fmaxf(S4[2][2], S4[2][3])),
                                     fmaxf(fmaxf(S4[3][0], S4[3][1]), fmaxf(S4[3][2], S4[3][3]))));
                tm = fmaxf(tm, __shfl_xor(tm, 16));
                tm = fmaxf(tm, __shfl_xor(tm, 32));
                const float mn  = fmaxf(m_[f], tm);
                const float mnc = fmaxf(mn, -3.0e38f);
                const float al  = exp2f(fminf(m_[f] - mnc, 0.f));
                float rs = 0.f;
                #pragma unroll
                for (int nt = 0; nt < 4; ++nt) {
                    #pragma unroll
                    for (int r = 0; r < 4; ++r) {
                        float p = exp2f(S4[nt][r] - mnc);
                        S4[nt][r] = p;
                        rs += p;
                    }
                    pf[f][nt][0] = (_Float16)S4[nt][0];
                    pf[f][nt][1] = (_Float16)S4[nt][1];
                    pf[f][nt][2] = (_Float16)S4[nt][2];
                    pf[f][nt][3] = (_Float16)S4[nt][3];
                }
                rs += __shfl_xor(rs, 16);
                rs += __shfl_xor(rs, 32);
                l_[f] = l_[f] * al + rs;
                m_[f] = mn;
                #pragma unroll
                for (int at = 0; at < 4; ++at) O4[f][at] *= al;
            }

            // ---- O^T += V^T . P^T: va read once, feeds both frags ----
            __builtin_amdgcn_s_setprio(1);
            #pragma unroll
            for (int at = 0; at < 4; ++at) {
                #pragma unroll
                for (int nt = 0; nt < 4; ++nt) {
                    half4 va = *(const half4*)(Vw + at * 1024 + c * 64 +
                                               ((nt * 16 + g * 4) ^ csw));
                    O4[0][at] = __builtin_amdgcn_mfma_f32_16x16x16f16(va, pf[0][nt], O4[0][at], 0, 0, 0);
                    O4[1][at] = __builtin_amdgcn_mfma_f32_16x16x16f16(va, pf[1][nt], O4[1][at], 0, 0, 0);
                }
            }
            __builtin_amdgcn_s_setprio(0);
        }
        cur ^= 1;
    }
    #undef STAGE_KV

    // ---- epilogue: 2 passes (one per frag), combine ph pairs via LDS ----
    float*  Of  = (float*)smem;                 // [wid][at][lane][r]  32 KB
    float2* mlb = (float2*)(smem + 16384);      // byte off 32768, 1 KB
    #pragma unroll
    for (int f = 0; f < 2; ++f) {
        __syncthreads();
        #pragma unroll
        for (int at = 0; at < 4; ++at) {
            float4 v; v.x = O4[f][at][0]; v.y = O4[f][at][1];
            v.z = O4[f][at][2]; v.w = O4[f][at][3];
            ((float4*)Of)[wid * 256 + at * 64 + lane] = v;
        }
        if (g == 0) { float2 ml; ml.x = m_[f]; ml.y = l_[f]; mlb[wid * 16 + c] = ml; }
        __syncthreads();

        const int q64 = t >> 3, seg = t & 7;
        const int qs = q64 >> 4, cc = q64 & 15;
        const int rowq = 32 * qs + 16 * f + cc;
        const float2 A0 = mlb[(2 * qs) * 16 + cc];
        const float2 A1 = mlb[(2 * qs + 1) * 16 + cc];
        const float mf = fmaxf(A0.x, A1.x);
        const float mc = fmaxf(mf, -3.0e38f);
        const float w0 = exp2f(A0.x - mc);
        const float w1 = exp2f(A1.x - mc);
        const float ls = w0 * A0.y + w1 * A1.y;
        float res[8];
        #pragma unroll
        for (int u2 = 0; u2 < 8; ++u2) {
            const int a = seg * 8 + u2;
            const int at = a >> 4, gg = (a >> 2) & 3, r = a & 3;
            const int i0 = ((2 * qs) * 256 + at * 64 + gg * 16 + cc) * 4 + r;
            const int i1 = ((2 * qs + 1) * 256 + at * 64 + gg * 16 + cc) * 4 + r;
            res[u2] = w0 * Of[i0] + w1 * Of[i1];
        }
        float* p = poB + (size_t)j * M_ * A_ + base + (size_t)(q0 + rowq) * A_ + seg * 8;
        *(float4*)(p)     = make_float4(res[0], res[1], res[2], res[3]);
        *(float4*)(p + 4) = make_float4(res[4], res[5], res[6], res[7]);
        if (seg == 0) {
            float2 ml; ml.x = mf; ml.y = ls;
            mlB[(size_t)j * M_ + b * L_ + q0 + rowq] = ml;
        }
    }
}

// ---------------------------------------------------------------------------
// merge: final = sum_j(Oj*wj) / sum_j(lj*wj) over nch(qt) chunks, computed
// ONLINE with a statically-unrolled predicated loop (no runtime-indexed
// array -> no scratch). grid (1024), block 256.
// ---------------------------------------------------------------------------
__global__ __launch_bounds__(256) void merge_kernel(
    float* __restrict__ out, const float* __restrict__ poB,
    const float2* __restrict__ mlB)
{
    const int tg = blockIdx.x * 256 + threadIdx.x;   // 262144 float4s
    const int q = tg >> 4;
    const int qt = (q & (L_ - 1)) >> 7;              // 128-row q-tiles
    const int nch = (qt + 4) >> 2;                   // ceil((2qt+2)/8)
    float mf = -INFINITY, den = 0.f;
    float4 acc = make_float4(0.f, 0.f, 0.f, 0.f);
    #pragma unroll
    for (int jj = 0; jj < 8; ++jj) {
        if (jj < nch) {
            const float2 aj = mlB[(size_t)jj * M_ + q];
            const float mn = fmaxf(mf, aj.x);
            const float mc = fmaxf(mn, -3.0e38f);
            const float sc = exp2f(fminf(mf - mc, 0.f));
            const float wj = exp2f(aj.x - mc);
            const float4 o = ((const float4*)(poB + (size_t)jj * M_ * A_))[tg];
            acc.x = acc.x * sc + o.x * wj;
            acc.y = acc.y * sc + o.y * wj;
            acc.z = acc.z * sc + o.z * wj;
            acc.w = acc.w * sc + o.w * wj;
            den = den * sc + aj.y * wj;
            mf = mn;
        }
    }
    const float inv = 1.f / den;
    float4 r;
    r.x = acc.x * inv; r.y = acc.y * inv; r.z = acc.z * inv; r.w = acc.w * inv;
    ((float4*)out)[tg] = r;
}

// ---------------------------------------------------------------------------
extern "C" void kernel_launch(void* const* d_in, const int* in_sizes, int n_in,
                              void* d_out, int out_size, void* d_ws, size_t ws_size,
                              hipStream_t stream) {
    const float* x  = (const float*)d_in[0];
    const float* Wq = (const float*)d_in[1];
    const float* Wk = (const float*)d_in[2];
    const float* Wv = (const float*)d_in[3];

    char* ws = (char*)d_ws;
    unsigned short* qb = (unsigned short*)(ws);                    // 2 MB
    unsigned short* kb = (unsigned short*)(ws + (2u << 20));       // 2 MB
    unsigned short* vt = (unsigned short*)(ws + (4u << 20));       // 2 MB
    unsigned short* wt = (unsigned short*)(ws + (6u << 20));       // 96 KB (128 KB reserved)
    char* p0 = ws + (6u << 20) + (128u << 10);
    float*  poB = (float*)(p0);                                    // 8 x 4 MB
    float2* mlB = (float2*)(p0 + (32u << 20));                     // 8 x 128 KB
    float* out = (float*)d_out;

    hipLaunchKernelGGL(wconv_kernel, dim3(3), dim3(256), 0, stream, Wq, Wk, Wv, wt);
    hipLaunchKernelGGL(proj_kernel, dim3(M_ / 32), dim3(384), 0, stream, x, wt, qb, kb, vt);
    hipLaunchKernelGGL(attn_kernel, dim3(576), dim3(512), 0, stream,
                       qb, kb, vt, poB, mlB);
    hipLaunchKernelGGL(merge_kernel, dim3(1024), dim3(256), 0, stream,
                       out, poB, mlB);
}